// Round 5
// baseline (628.392 us; speedup 1.0000x reference)
//
#include <hip/hip_runtime.h>
#include <hip/hip_bf16.h>

// messages = relu(concat(node[src], node[tgt], edge) @ W + b) -> segment_sum by tgt
// R4 (resubmit after infra timeout): GEMM in ORIGINAL edge order (edge_feat
// streamed, msg written coalesced); pool does the permuted gather via CSR
// (hist/scan/perm are the R2-proven kernels).

using s16x8 = __attribute__((ext_vector_type(8))) short;
using f32x4 = __attribute__((ext_vector_type(4))) float;

static __device__ __forceinline__ ushort f2bf(float f) {
    union { __hip_bfloat16 h; ushort u; } cv;
    cv.h = __float2bfloat16(f);
    return cv.u;
}
static __device__ __forceinline__ float bf2f(ushort u) {
    union { unsigned u; float f; } cv;
    cv.u = ((unsigned)u) << 16;
    return cv.f;
}

// ---- W[192][64] f32 -> WT[64][192] bf16 ----
__global__ void prep_wt(const float* __restrict__ W, ushort* __restrict__ WT) {
    int idx = blockIdx.x * blockDim.x + threadIdx.x;
    if (idx < 64 * 192) {
        int n = idx / 192, k = idx % 192;
        WT[idx] = f2bf(W[k * 64 + n]);
    }
}

// ---- Histogram over targets (R2-proven) ----
__global__ void hist_tgt(const int* __restrict__ tgt, int* __restrict__ counts, int n_edges) {
    int i = blockIdx.x * blockDim.x + threadIdx.x;
    if (i < n_edges) atomicAdd(&counts[tgt[i]], 1);
}

// ---- Exclusive scan of counts (single block, R2-proven) ----
__global__ __launch_bounds__(1024) void scan_counts(
    const int* __restrict__ counts, int* __restrict__ offsets, int* __restrict__ woff,
    int n_nodes, int n_edges)
{
    __shared__ int wsum[16];
    __shared__ int base_s;
    const int tid = threadIdx.x, lane = tid & 63, wid = tid >> 6;
    if (tid == 0) base_s = 0;
    __syncthreads();
    for (int c0 = 0; c0 < n_nodes; c0 += 1024) {
        const int idx = c0 + tid;
        const int v = (idx < n_nodes) ? counts[idx] : 0;
        int x = v;
#pragma unroll
        for (int o = 1; o < 64; o <<= 1) { int t = __shfl_up(x, o, 64); if (lane >= o) x += t; }
        if (lane == 63) wsum[wid] = x;
        __syncthreads();
        if (tid < 16) {
            int w = wsum[tid];
#pragma unroll
            for (int o = 1; o < 16; o <<= 1) { int t = __shfl_up(w, o, 16); if (tid >= o) w += t; }
            wsum[tid] = w;
        }
        __syncthreads();
        const int wbase = (wid == 0) ? 0 : wsum[wid - 1];
        const int excl = base_s + wbase + x - v;
        if (idx < n_nodes) { offsets[idx] = excl; woff[idx] = excl; }
        const int total = wsum[15];
        __syncthreads();
        if (tid == 0) base_s += total;
        __syncthreads();
    }
    if (threadIdx.x == 0) offsets[n_nodes] = n_edges;
}

// ---- Scatter edge ids into tgt-sorted positions (R2-proven) ----
__global__ void build_perm(const int* __restrict__ tgt, int* __restrict__ woff,
                           int* __restrict__ perm, int n_edges) {
    int i = blockIdx.x * blockDim.x + threadIdx.x;
    if (i < n_edges) {
        int p = atomicAdd(&woff[tgt[i]], 1);
        perm[p] = i;
    }
}

// ---- Direct-register MFMA gather-GEMM in ORIGINAL edge order ----
// edge_feat is streamed sequentially; node rows are L2-resident gathers.
// msg written coalesced in edge order (bf16).
__global__ __launch_bounds__(256) void edge_gemm_stream(
    const float* __restrict__ node, const float* __restrict__ edgef,
    const int* __restrict__ src, const int* __restrict__ tgt,
    const ushort* __restrict__ WT, const float* __restrict__ bias,
    ushort* __restrict__ msg, int n_edges)
{
    // Only LDS: per-wave epilogue transpose buffer, padded 64->72.
    __shared__ __align__(16) ushort T[4][16][72];

    const int wave = threadIdx.x >> 6, lane = threadIdx.x & 63;
    const int g = lane >> 4, r = lane & 15;
    const int tile0 = blockIdx.x * 64 + wave * 16;

    int pos = tile0 + r; if (pos >= n_edges) pos = n_edges - 1;
    const int si = src[pos], ti = tgt[pos];

    const float* base0 = node  + (size_t)si * 64;
    const float* base1 = node  + (size_t)ti * 64;
    const float* base2 = edgef + (size_t)pos * 64;

    // A fragment: lane(r,g) holds row=pos, k = ks*32 + g*8 .. +8 (per-segment slices).
    f32x4 lo[6], hi[6];
#pragma unroll
    for (int ks = 0; ks < 6; ++ks) {
        const float* b = (ks < 2) ? base0 : (ks < 4) ? base1 : base2;
        const float* p = b + (ks & 1) * 32 + g * 8;
        lo[ks] = *reinterpret_cast<const f32x4*>(p);
        hi[ks] = *reinterpret_cast<const f32x4*>(p + 4);
    }

    f32x4 acc[4] = {{0.f,0.f,0.f,0.f},{0.f,0.f,0.f,0.f},{0.f,0.f,0.f,0.f},{0.f,0.f,0.f,0.f}};
#pragma unroll
    for (int ks = 0; ks < 6; ++ks) {
        s16x8 a;
#pragma unroll
        for (int j = 0; j < 4; ++j) { a[j] = (short)f2bf(lo[ks][j]); a[4 + j] = (short)f2bf(hi[ks][j]); }
#pragma unroll
        for (int nt = 0; nt < 4; ++nt) {
            const s16x8 bf = *reinterpret_cast<const s16x8*>(WT + (nt * 16 + r) * 192 + ks * 32 + g * 8);
            acc[nt] = __builtin_amdgcn_mfma_f32_16x16x32_bf16(a, bf, acc[nt], 0, 0, 0);
        }
    }

    // Epilogue: relu(acc+b) -> LDS transpose -> coalesced bf16 store (edge order).
    // C/D layout: col = lane&15, row = (lane>>4)*4 + j
#pragma unroll
    for (int nt = 0; nt < 4; ++nt) {
        const float bv = bias[nt * 16 + r];
#pragma unroll
        for (int j = 0; j < 4; ++j)
            T[wave][g * 4 + j][nt * 16 + r] = f2bf(fmaxf(acc[nt][j] + bv, 0.0f));
    }
    __syncthreads();
    const int row = lane >> 2, q = lane & 3;
    if (tile0 + row < n_edges) {
        const s16x8 m0 = *reinterpret_cast<const s16x8*>(&T[wave][row][q * 16]);
        const s16x8 m1 = *reinterpret_cast<const s16x8*>(&T[wave][row][q * 16 + 8]);
        const size_t p = (size_t)(tile0 + row) * 64 + q * 16;
        *reinterpret_cast<s16x8*>(msg + p) = m0;
        *reinterpret_cast<s16x8*>(msg + p + 8) = m1;
    }
}

// ---- Per-node pooling via CSR: gather msg rows by perm, 16 B/lane, 8 rows in flight ----
__global__ __launch_bounds__(256) void pool_gather(
    const ushort* __restrict__ msg, const int* __restrict__ offsets,
    const int* __restrict__ perm, float* __restrict__ out, int n_nodes)
{
    const int wave = threadIdx.x >> 6, lane = threadIdx.x & 63;
    const int n = blockIdx.x * 4 + wave;
    if (n >= n_nodes) return;
    const int s = offsets[n], e = offsets[n + 1];
    const int c = lane & 7;    // feature chunk (8 features, 16 B)
    const int rg = lane >> 3;  // row group: 8 rows in flight
    float acc[8] = {0.f,0.f,0.f,0.f,0.f,0.f,0.f,0.f};
    for (int i = s + rg; i < e; i += 8) {
        const int row = perm[i];
        const s16x8 v = *reinterpret_cast<const s16x8*>(msg + (size_t)row * 64 + c * 8);
#pragma unroll
        for (int j = 0; j < 8; ++j) acc[j] += bf2f((ushort)v[j]);
    }
#pragma unroll
    for (int j = 0; j < 8; ++j) {
        acc[j] += __shfl_xor(acc[j], 8, 64);
        acc[j] += __shfl_xor(acc[j], 16, 64);
        acc[j] += __shfl_xor(acc[j], 32, 64);
    }
    if (rg == 0) {
        const f32x4 o0 = {acc[0], acc[1], acc[2], acc[3]};
        const f32x4 o1 = {acc[4], acc[5], acc[6], acc[7]};
        *reinterpret_cast<f32x4*>(out + (size_t)n * 64 + c * 8) = o0;
        *reinterpret_cast<f32x4*>(out + (size_t)n * 64 + c * 8 + 4) = o1;
    }
}

// ---- Fallback: atomic scatter (only if ws too small) ----
__global__ __launch_bounds__(256) void edge_gemm_atomic(
    const float* __restrict__ node, const float* __restrict__ edgef,
    const int* __restrict__ src, const int* __restrict__ tgt,
    const ushort* __restrict__ WT, const float* __restrict__ bias,
    float* __restrict__ out, int n_edges)
{
    const int lane = threadIdx.x & 63;
    const int g = lane >> 4, r = lane & 15;
    const int tile0 = blockIdx.x * 64 + (threadIdx.x >> 6) * 16;
    int pos = tile0 + r; if (pos >= n_edges) pos = n_edges - 1;
    const int si = src[pos], ti = tgt[pos];
    const float* base0 = node + (size_t)si * 64;
    const float* base1 = node + (size_t)ti * 64;
    const float* base2 = edgef + (size_t)pos * 64;
    f32x4 acc[4] = {{0.f,0.f,0.f,0.f},{0.f,0.f,0.f,0.f},{0.f,0.f,0.f,0.f},{0.f,0.f,0.f,0.f}};
#pragma unroll
    for (int ks = 0; ks < 6; ++ks) {
        const float* b = (ks < 2) ? base0 : (ks < 4) ? base1 : base2;
        const float* p = b + (ks & 1) * 32 + g * 8;
        const f32x4 lo = *reinterpret_cast<const f32x4*>(p);
        const f32x4 hi = *reinterpret_cast<const f32x4*>(p + 4);
        s16x8 a;
#pragma unroll
        for (int j = 0; j < 4; ++j) { a[j] = (short)f2bf(lo[j]); a[4 + j] = (short)f2bf(hi[j]); }
#pragma unroll
        for (int nt = 0; nt < 4; ++nt) {
            const s16x8 bf = *reinterpret_cast<const s16x8*>(WT + (nt * 16 + r) * 192 + ks * 32 + g * 8);
            acc[nt] = __builtin_amdgcn_mfma_f32_16x16x32_bf16(a, bf, acc[nt], 0, 0, 0);
        }
    }
#pragma unroll
    for (int nt = 0; nt < 4; ++nt) {
        const float bv = bias[nt * 16 + r];
#pragma unroll
        for (int j = 0; j < 4; ++j) {
            const int e = tile0 + g * 4 + j;
            if (e < n_edges) {
                float v = fmaxf(acc[nt][j] + bv, 0.0f);
                unsafeAtomicAdd(out + (size_t)tgt[e] * 64 + nt * 16 + r, v);
            }
        }
    }
}

extern "C" void kernel_launch(void* const* d_in, const int* in_sizes, int n_in,
                              void* d_out, int out_size, void* d_ws, size_t ws_size,
                              hipStream_t stream) {
    const float* node  = (const float*)d_in[0];
    const float* edgef = (const float*)d_in[1];
    const int*   src   = (const int*)d_in[2];
    const int*   tgt   = (const int*)d_in[3];
    const float* W     = (const float*)d_in[4];
    const float* bias  = (const float*)d_in[5];
    float* out = (float*)d_out;
    const int n_edges = in_sizes[2];
    const int n_nodes = in_sizes[0] / 64;

    char* ws = (char*)d_ws;
    size_t cur = 0;
    auto take = [&](size_t b) { size_t s = cur; cur = (cur + b + 255) & ~(size_t)255; return s; };
    const size_t oWT   = take((size_t)64 * 192 * 2);
    const size_t oCnt  = take((size_t)n_nodes * 4);
    const size_t oOff  = take((size_t)(n_nodes + 1) * 4);
    const size_t oWoff = take((size_t)n_nodes * 4);
    const size_t oPerm = take((size_t)n_edges * 4);
    const size_t oMsg  = take((size_t)n_edges * 64 * 2);
    const bool sorted_ok = (cur <= ws_size);

    ushort* WT = (ushort*)(ws + oWT);
    prep_wt<<<48, 256, 0, stream>>>(W, WT);

    if (sorted_ok) {
        int* counts  = (int*)(ws + oCnt);
        int* offsets = (int*)(ws + oOff);
        int* woff    = (int*)(ws + oWoff);
        int* perm    = (int*)(ws + oPerm);
        ushort* msg  = (ushort*)(ws + oMsg);

        hipMemsetAsync(counts, 0, (size_t)n_nodes * 4, stream);
        hist_tgt<<<(n_edges + 255) / 256, 256, 0, stream>>>(tgt, counts, n_edges);
        scan_counts<<<1, 1024, 0, stream>>>(counts, offsets, woff, n_nodes, n_edges);
        build_perm<<<(n_edges + 255) / 256, 256, 0, stream>>>(tgt, woff, perm, n_edges);
        edge_gemm_stream<<<(n_edges + 63) / 64, 256, 0, stream>>>(
            node, edgef, src, tgt, WT, bias, msg, n_edges);
        pool_gather<<<(n_nodes + 3) / 4, 256, 0, stream>>>(msg, offsets, perm, out, n_nodes);
    } else {
        hipMemsetAsync(d_out, 0, (size_t)out_size * sizeof(float), stream);
        edge_gemm_atomic<<<(n_edges + 63) / 64, 256, 0, stream>>>(
            node, edgef, src, tgt, WT, bias, out, n_edges);
    }
}

// Round 7
// 503.639 us; speedup vs baseline: 1.2477x; 1.2477x over previous
//
#include <hip/hip_runtime.h>
#include <hip/hip_bf16.h>

// messages = relu(concat(node[src], node[tgt], edge) @ W + b) -> segment_sum by tgt
// R6 (resubmit after infra timeout): persistent-wave software-pipelined MFMA
// gather-GEMM (prefetch depth 2, W in LDS so B-reads use lgkmcnt and never
// drain the vmcnt prefetch queue, wave-local epilogue without block barriers).
// Sort+pool = R5-proven verbatim.

using s16x8 = __attribute__((ext_vector_type(8))) short;
using f32x4 = __attribute__((ext_vector_type(4))) float;

#define WT_LD 200   // padded LDS row stride (ushorts): 400 B -> 2-way bank aliasing (free)

static __device__ __forceinline__ ushort f2bf(float f) {
    union { __hip_bfloat16 h; ushort u; } cv;
    cv.h = __float2bfloat16(f);
    return cv.u;
}
static __device__ __forceinline__ float bf2f(ushort u) {
    union { unsigned u; float f; } cv;
    cv.u = ((unsigned)u) << 16;
    return cv.f;
}

// ---- W[192][64] f32 -> WT[64][192] bf16 ----
__global__ void prep_wt(const float* __restrict__ W, ushort* __restrict__ WT) {
    int idx = blockIdx.x * blockDim.x + threadIdx.x;
    if (idx < 64 * 192) {
        int n = idx / 192, k = idx % 192;
        WT[idx] = f2bf(W[k * 64 + n]);
    }
}

// ---- Histogram over targets (R2-proven) ----
__global__ void hist_tgt(const int* __restrict__ tgt, int* __restrict__ counts, int n_edges) {
    int i = blockIdx.x * blockDim.x + threadIdx.x;
    if (i < n_edges) atomicAdd(&counts[tgt[i]], 1);
}

// ---- Exclusive scan of counts (single block, R2-proven) ----
__global__ __launch_bounds__(1024) void scan_counts(
    const int* __restrict__ counts, int* __restrict__ offsets, int* __restrict__ woff,
    int n_nodes, int n_edges)
{
    __shared__ int wsum[16];
    __shared__ int base_s;
    const int tid = threadIdx.x, lane = tid & 63, wid = tid >> 6;
    if (tid == 0) base_s = 0;
    __syncthreads();
    for (int c0 = 0; c0 < n_nodes; c0 += 1024) {
        const int idx = c0 + tid;
        const int v = (idx < n_nodes) ? counts[idx] : 0;
        int x = v;
#pragma unroll
        for (int o = 1; o < 64; o <<= 1) { int t = __shfl_up(x, o, 64); if (lane >= o) x += t; }
        if (lane == 63) wsum[wid] = x;
        __syncthreads();
        if (tid < 16) {
            int w = wsum[tid];
#pragma unroll
            for (int o = 1; o < 16; o <<= 1) { int t = __shfl_up(w, o, 16); if (tid >= o) w += t; }
            wsum[tid] = w;
        }
        __syncthreads();
        const int wbase = (wid == 0) ? 0 : wsum[wid - 1];
        const int excl = base_s + wbase + x - v;
        if (idx < n_nodes) { offsets[idx] = excl; woff[idx] = excl; }
        const int total = wsum[15];
        __syncthreads();
        if (tid == 0) base_s += total;
        __syncthreads();
    }
    if (threadIdx.x == 0) offsets[n_nodes] = n_edges;
}

// ---- Scatter edge ids into tgt-sorted positions (R2-proven) ----
__global__ void build_perm(const int* __restrict__ tgt, int* __restrict__ woff,
                           int* __restrict__ perm, int n_edges) {
    int i = blockIdx.x * blockDim.x + threadIdx.x;
    if (i < n_edges) {
        int p = atomicAdd(&woff[tgt[i]], 1);
        perm[p] = i;
    }
}

// ---- Persistent-wave pipelined MFMA gather-GEMM (original edge order) ----
__global__ __launch_bounds__(256, 4) void edge_gemm_pipe(
    const float* __restrict__ node, const float* __restrict__ edgef,
    const int* __restrict__ src, const int* __restrict__ tgt,
    const ushort* __restrict__ WT, const float* __restrict__ bias,
    ushort* __restrict__ msg, int n_edges)
{
    __shared__ __align__(16) ushort WTs[64][WT_LD];   // 25600 B
    __shared__ __align__(16) ushort T[4][16][72];     //  9216 B (wave-private quadrants)

    const int wave = threadIdx.x >> 6, lane = threadIdx.x & 63;
    const int g = lane >> 4, r = lane & 15;

    // Stage WT[64][192] -> LDS [64][200] once (16 B chunks, 6 per thread).
    for (int c = threadIdx.x; c < 1536; c += 256) {
        const int row = c / 24, col = (c % 24) * 8;
        *reinterpret_cast<s16x8*>(&WTs[row][col]) =
            *reinterpret_cast<const s16x8*>(WT + row * 192 + col);
    }
    float bv[4];
#pragma unroll
    for (int nt = 0; nt < 4; ++nt) bv[nt] = bias[nt * 16 + r];
    __syncthreads();

    const int ntiles = (n_edges + 15) >> 4;
    const int nw = gridDim.x << 2;                 // total waves
    int t = blockIdx.x * 4 + wave;
    if (t >= ntiles) return;                       // (after the only barrier)

    auto posof = [&](int tt) { int p = tt * 16 + r; return (p < n_edges) ? p : n_edges - 1; };

    // ---- pipeline prologue: F(t) issued+converted, idx(t+nw) loaded ----
    int p = posof(t);
    int si = src[p], ti = tgt[p];
    f32x4 lo[6], hi[6];
    {
        const float* b0 = node + (size_t)si * 64;
        const float* b1 = node + (size_t)ti * 64;
        const float* b2 = edgef + (size_t)p * 64;
#pragma unroll
        for (int ks = 0; ks < 6; ++ks) {
            const float* bb = (ks < 2) ? b0 : (ks < 4) ? b1 : b2;
            const float* pp = bb + (ks & 1) * 32 + g * 8;
            lo[ks] = *reinterpret_cast<const f32x4*>(pp);
            hi[ks] = *reinterpret_cast<const f32x4*>(pp + 4);
        }
    }
    int pN = posof(t + nw);
    int siN = src[pN], tiN = tgt[pN];
    s16x8 A[6];
#pragma unroll
    for (int ks = 0; ks < 6; ++ks)
#pragma unroll
        for (int j = 0; j < 4; ++j) { A[ks][j] = (short)f2bf(lo[ks][j]); A[ks][4 + j] = (short)f2bf(hi[ks][j]); }

    // ---- main loop ----
    while (true) {
        const bool have_next = (t + nw) < ntiles;
        // (1) issue F(t+nw): 12 independent 16 B loads (oldest in vmcnt queue)
        if (have_next) {
            const float* b0 = node + (size_t)siN * 64;
            const float* b1 = node + (size_t)tiN * 64;
            const float* b2 = edgef + (size_t)pN * 64;
#pragma unroll
            for (int ks = 0; ks < 6; ++ks) {
                const float* bb = (ks < 2) ? b0 : (ks < 4) ? b1 : b2;
                const float* pp = bb + (ks & 1) * 32 + g * 8;
                lo[ks] = *reinterpret_cast<const f32x4*>(pp);
                hi[ks] = *reinterpret_cast<const f32x4*>(pp + 4);
            }
        }
        // (2) issue idx(t+2nw)
        const int pN2 = posof(t + 2 * nw);
        const int siN2 = src[pN2], tiN2 = tgt[pN2];

        // (3) MFMA from registers (A) + LDS (B). lz launders the LDS base so
        // LICM can't hoist 24 loop-invariant b128 reads into 96 VGPRs.
        int lz;
        asm volatile("v_mov_b32 %0, 0" : "=v"(lz));
        const ushort* wbase = &WTs[0][0] + lz;
        f32x4 acc[4] = {{0.f,0.f,0.f,0.f},{0.f,0.f,0.f,0.f},{0.f,0.f,0.f,0.f},{0.f,0.f,0.f,0.f}};
#pragma unroll
        for (int ks = 0; ks < 6; ++ks)
#pragma unroll
            for (int nt = 0; nt < 4; ++nt) {
                const s16x8 bf = *reinterpret_cast<const s16x8*>(
                    wbase + (nt * 16 + r) * WT_LD + ks * 32 + g * 8);
                acc[nt] = __builtin_amdgcn_mfma_f32_16x16x32_bf16(A[ks], bf, acc[nt], 0, 0, 0);
            }

        // (4) wave-local epilogue: relu(acc+b) -> LDS transpose -> coalesced store.
        // C/D layout: col = lane&15, row = (lane>>4)*4 + j. T[wave] is private to
        // this wave; per-wave in-order LDS + lgkmcnt(0) replaces __syncthreads.
        const int tile0 = t * 16;
#pragma unroll
        for (int nt = 0; nt < 4; ++nt)
#pragma unroll
            for (int j = 0; j < 4; ++j)
                T[wave][g * 4 + j][nt * 16 + r] = f2bf(fmaxf(acc[nt][j] + bv[nt], 0.0f));
        asm volatile("s_waitcnt lgkmcnt(0)" ::: "memory");
        {
            const int row = lane >> 2, q = lane & 3;
            if (tile0 + row < n_edges) {
                const s16x8 m0 = *reinterpret_cast<const s16x8*>(&T[wave][row][q * 16]);
                const s16x8 m1 = *reinterpret_cast<const s16x8*>(&T[wave][row][q * 16 + 8]);
                const size_t op = (size_t)(tile0 + row) * 64 + q * 16;
                *reinterpret_cast<s16x8*>(msg + op) = m0;
                *reinterpret_cast<s16x8*>(msg + op + 8) = m1;
            }
        }

        if (!have_next) break;
        t += nw;
        // (5) rotate: convert F(t) -> A (compiler waits vmcnt for F only; idx
        // loads are younger and stay outstanding).
#pragma unroll
        for (int ks = 0; ks < 6; ++ks)
#pragma unroll
            for (int j = 0; j < 4; ++j) { A[ks][j] = (short)f2bf(lo[ks][j]); A[ks][4 + j] = (short)f2bf(hi[ks][j]); }
        pN = pN2; siN = siN2; tiN = tiN2;
    }
}

// ---- Per-node pooling via CSR gather (R5-proven) ----
__global__ __launch_bounds__(256) void pool_gather(
    const ushort* __restrict__ msg, const int* __restrict__ offsets,
    const int* __restrict__ perm, float* __restrict__ out, int n_nodes)
{
    const int wave = threadIdx.x >> 6, lane = threadIdx.x & 63;
    const int n = blockIdx.x * 4 + wave;
    if (n >= n_nodes) return;
    const int s = offsets[n], e = offsets[n + 1];
    const int c = lane & 7;
    const int rg = lane >> 3;
    float acc[8] = {0.f,0.f,0.f,0.f,0.f,0.f,0.f,0.f};
    for (int i = s + rg; i < e; i += 8) {
        const int row = perm[i];
        const s16x8 v = *reinterpret_cast<const s16x8*>(msg + (size_t)row * 64 + c * 8);
#pragma unroll
        for (int j = 0; j < 8; ++j) acc[j] += bf2f((ushort)v[j]);
    }
#pragma unroll
    for (int j = 0; j < 8; ++j) {
        acc[j] += __shfl_xor(acc[j], 8, 64);
        acc[j] += __shfl_xor(acc[j], 16, 64);
        acc[j] += __shfl_xor(acc[j], 32, 64);
    }
    if (rg == 0) {
        const f32x4 o0 = {acc[0], acc[1], acc[2], acc[3]};
        const f32x4 o1 = {acc[4], acc[5], acc[6], acc[7]};
        *reinterpret_cast<f32x4*>(out + (size_t)n * 64 + c * 8) = o0;
        *reinterpret_cast<f32x4*>(out + (size_t)n * 64 + c * 8 + 4) = o1;
    }
}

// ---- Fallback: atomic scatter (only if ws too small) ----
__global__ __launch_bounds__(256) void edge_gemm_atomic(
    const float* __restrict__ node, const float* __restrict__ edgef,
    const int* __restrict__ src, const int* __restrict__ tgt,
    const ushort* __restrict__ WT, const float* __restrict__ bias,
    float* __restrict__ out, int n_edges)
{
    const int lane = threadIdx.x & 63;
    const int g = lane >> 4, r = lane & 15;
    const int tile0 = blockIdx.x * 64 + (threadIdx.x >> 6) * 16;
    int pos = tile0 + r; if (pos >= n_edges) pos = n_edges - 1;
    const int si = src[pos], ti = tgt[pos];
    const float* base0 = node + (size_t)si * 64;
    const float* base1 = node + (size_t)ti * 64;
    const float* base2 = edgef + (size_t)pos * 64;
    f32x4 acc[4] = {{0.f,0.f,0.f,0.f},{0.f,0.f,0.f,0.f},{0.f,0.f,0.f,0.f},{0.f,0.f,0.f,0.f}};
#pragma unroll
    for (int ks = 0; ks < 6; ++ks) {
        const float* b = (ks < 2) ? base0 : (ks < 4) ? base1 : base2;
        const float* p = b + (ks & 1) * 32 + g * 8;
        const f32x4 lo = *reinterpret_cast<const f32x4*>(p);
        const f32x4 hi = *reinterpret_cast<const f32x4*>(p + 4);
        s16x8 a;
#pragma unroll
        for (int j = 0; j < 4; ++j) { a[j] = (short)f2bf(lo[j]); a[4 + j] = (short)f2bf(hi[j]); }
#pragma unroll
        for (int nt = 0; nt < 4; ++nt) {
            const s16x8 bf = *reinterpret_cast<const s16x8*>(WT + (nt * 16 + r) * 192 + ks * 32 + g * 8);
            acc[nt] = __builtin_amdgcn_mfma_f32_16x16x32_bf16(a, bf, acc[nt], 0, 0, 0);
        }
    }
#pragma unroll
    for (int nt = 0; nt < 4; ++nt) {
        const float bv = bias[nt * 16 + r];
#pragma unroll
        for (int j = 0; j < 4; ++j) {
            const int e = tile0 + g * 4 + j;
            if (e < n_edges) {
                float v = fmaxf(acc[nt][j] + bv, 0.0f);
                unsafeAtomicAdd(out + (size_t)tgt[e] * 64 + nt * 16 + r, v);
            }
        }
    }
}

extern "C" void kernel_launch(void* const* d_in, const int* in_sizes, int n_in,
                              void* d_out, int out_size, void* d_ws, size_t ws_size,
                              hipStream_t stream) {
    const float* node  = (const float*)d_in[0];
    const float* edgef = (const float*)d_in[1];
    const int*   src   = (const int*)d_in[2];
    const int*   tgt   = (const int*)d_in[3];
    const float* W     = (const float*)d_in[4];
    const float* bias  = (const float*)d_in[5];
    float* out = (float*)d_out;
    const int n_edges = in_sizes[2];
    const int n_nodes = in_sizes[0] / 64;

    char* ws = (char*)d_ws;
    size_t cur = 0;
    auto take = [&](size_t b) { size_t s = cur; cur = (cur + b + 255) & ~(size_t)255; return s; };
    const size_t oWT   = take((size_t)64 * 192 * 2);
    const size_t oCnt  = take((size_t)n_nodes * 4);
    const size_t oOff  = take((size_t)(n_nodes + 1) * 4);
    const size_t oWoff = take((size_t)n_nodes * 4);
    const size_t oPerm = take((size_t)n_edges * 4);
    const size_t oMsg  = take((size_t)n_edges * 64 * 2);
    const bool sorted_ok = (cur <= ws_size);

    ushort* WT = (ushort*)(ws + oWT);
    prep_wt<<<48, 256, 0, stream>>>(W, WT);

    if (sorted_ok) {
        int* counts  = (int*)(ws + oCnt);
        int* offsets = (int*)(ws + oOff);
        int* woff    = (int*)(ws + oWoff);
        int* perm    = (int*)(ws + oPerm);
        ushort* msg  = (ushort*)(ws + oMsg);

        hipMemsetAsync(counts, 0, (size_t)n_nodes * 4, stream);
        hist_tgt<<<(n_edges + 255) / 256, 256, 0, stream>>>(tgt, counts, n_edges);
        scan_counts<<<1, 1024, 0, stream>>>(counts, offsets, woff, n_nodes, n_edges);
        build_perm<<<(n_edges + 255) / 256, 256, 0, stream>>>(tgt, woff, perm, n_edges);

        const int ntiles = (n_edges + 15) / 16;
        int blocks = 1024;
        if (blocks * 4 > ntiles) blocks = (ntiles + 3) / 4;
        edge_gemm_pipe<<<blocks, 256, 0, stream>>>(
            node, edgef, src, tgt, WT, bias, msg, n_edges);
        pool_gather<<<(n_nodes + 3) / 4, 256, 0, stream>>>(msg, offsets, perm, out, n_nodes);
    } else {
        hipMemsetAsync(d_out, 0, (size_t)out_size * sizeof(float), stream);
        edge_gemm_atomic<<<(n_edges + 63) / 64, 256, 0, stream>>>(
            node, edgef, src, tgt, WT, bias, out, n_edges);
    }
}

// Round 8
// 486.032 us; speedup vs baseline: 1.2929x; 1.0362x over previous
//
#include <hip/hip_runtime.h>
#include <hip/hip_bf16.h>

// messages = relu(concat(node[src], node[tgt], edge) @ W + b) -> segment_sum by tgt
// R8: rank-scatter. build_rank stores each edge's sorted position; the pipelined
// GEMM writes msg rows AT the sorted position (scattered 128B writes, latency-
// tolerant); pool reads contiguous runs with zero indirection (coalesced).
// GEMM pipeline + hist/scan = R7-proven verbatim.

using s16x8 = __attribute__((ext_vector_type(8))) short;
using f32x4 = __attribute__((ext_vector_type(4))) float;

#define WT_LD 200   // padded LDS row stride (ushorts): 400 B -> 2-way bank aliasing (free)

static __device__ __forceinline__ ushort f2bf(float f) {
    union { __hip_bfloat16 h; ushort u; } cv;
    cv.h = __float2bfloat16(f);
    return cv.u;
}
static __device__ __forceinline__ float bf2f(ushort u) {
    union { unsigned u; float f; } cv;
    cv.u = ((unsigned)u) << 16;
    return cv.f;
}

// ---- W[192][64] f32 -> WT[64][192] bf16 ----
__global__ void prep_wt(const float* __restrict__ W, ushort* __restrict__ WT) {
    int idx = blockIdx.x * blockDim.x + threadIdx.x;
    if (idx < 64 * 192) {
        int n = idx / 192, k = idx % 192;
        WT[idx] = f2bf(W[k * 64 + n]);
    }
}

// ---- Histogram over targets (R2-proven) ----
__global__ void hist_tgt(const int* __restrict__ tgt, int* __restrict__ counts, int n_edges) {
    int i = blockIdx.x * blockDim.x + threadIdx.x;
    if (i < n_edges) atomicAdd(&counts[tgt[i]], 1);
}

// ---- Exclusive scan of counts (single block, R2-proven) ----
__global__ __launch_bounds__(1024) void scan_counts(
    const int* __restrict__ counts, int* __restrict__ offsets, int* __restrict__ woff,
    int n_nodes, int n_edges)
{
    __shared__ int wsum[16];
    __shared__ int base_s;
    const int tid = threadIdx.x, lane = tid & 63, wid = tid >> 6;
    if (tid == 0) base_s = 0;
    __syncthreads();
    for (int c0 = 0; c0 < n_nodes; c0 += 1024) {
        const int idx = c0 + tid;
        const int v = (idx < n_nodes) ? counts[idx] : 0;
        int x = v;
#pragma unroll
        for (int o = 1; o < 64; o <<= 1) { int t = __shfl_up(x, o, 64); if (lane >= o) x += t; }
        if (lane == 63) wsum[wid] = x;
        __syncthreads();
        if (tid < 16) {
            int w = wsum[tid];
#pragma unroll
            for (int o = 1; o < 16; o <<= 1) { int t = __shfl_up(w, o, 16); if (tid >= o) w += t; }
            wsum[tid] = w;
        }
        __syncthreads();
        const int wbase = (wid == 0) ? 0 : wsum[wid - 1];
        const int excl = base_s + wbase + x - v;
        if (idx < n_nodes) { offsets[idx] = excl; woff[idx] = excl; }
        const int total = wsum[15];
        __syncthreads();
        if (tid == 0) base_s += total;
        __syncthreads();
    }
    if (threadIdx.x == 0) offsets[n_nodes] = n_edges;
}

// ---- rank[e] = sorted position of edge e (same atomic pattern as proven build_perm) ----
__global__ void build_rank(const int* __restrict__ tgt, int* __restrict__ woff,
                           int* __restrict__ rank, int n_edges) {
    int i = blockIdx.x * blockDim.x + threadIdx.x;
    if (i < n_edges) {
        rank[i] = atomicAdd(&woff[tgt[i]], 1);
    }
}

// ---- Persistent-wave pipelined MFMA gather-GEMM (original edge order),
//      message rows stored at SORTED positions via rank ----
__global__ __launch_bounds__(256, 4) void edge_gemm_pipe(
    const float* __restrict__ node, const float* __restrict__ edgef,
    const int* __restrict__ src, const int* __restrict__ tgt,
    const int* __restrict__ rank,
    const ushort* __restrict__ WT, const float* __restrict__ bias,
    ushort* __restrict__ msg, int n_edges)
{
    __shared__ __align__(16) ushort WTs[64][WT_LD];   // 25600 B
    __shared__ __align__(16) ushort T[4][16][72];     //  9216 B (wave-private quadrants)

    const int wave = threadIdx.x >> 6, lane = threadIdx.x & 63;
    const int g = lane >> 4, r = lane & 15;

    // Stage WT[64][192] -> LDS [64][200] once (16 B chunks, 6 per thread).
    for (int c = threadIdx.x; c < 1536; c += 256) {
        const int row = c / 24, col = (c % 24) * 8;
        *reinterpret_cast<s16x8*>(&WTs[row][col]) =
            *reinterpret_cast<const s16x8*>(WT + row * 192 + col);
    }
    float bv[4];
#pragma unroll
    for (int nt = 0; nt < 4; ++nt) bv[nt] = bias[nt * 16 + r];
    __syncthreads();

    const int ntiles = (n_edges + 15) >> 4;
    const int nw = gridDim.x << 2;                 // total waves
    int t = blockIdx.x * 4 + wave;
    if (t >= ntiles) return;                       // (after the only barrier)

    auto posof = [&](int tt) { int p = tt * 16 + r; return (p < n_edges) ? p : n_edges - 1; };

    // ---- pipeline prologue: F(t) issued+converted, idx(t+nw) loaded ----
    int p = posof(t);
    int si = src[p], ti = tgt[p];
    f32x4 lo[6], hi[6];
    {
        const float* b0 = node + (size_t)si * 64;
        const float* b1 = node + (size_t)ti * 64;
        const float* b2 = edgef + (size_t)p * 64;
#pragma unroll
        for (int ks = 0; ks < 6; ++ks) {
            const float* bb = (ks < 2) ? b0 : (ks < 4) ? b1 : b2;
            const float* pp = bb + (ks & 1) * 32 + g * 8;
            lo[ks] = *reinterpret_cast<const f32x4*>(pp);
            hi[ks] = *reinterpret_cast<const f32x4*>(pp + 4);
        }
    }
    int pN = posof(t + nw);
    int siN = src[pN], tiN = tgt[pN];
    s16x8 A[6];
#pragma unroll
    for (int ks = 0; ks < 6; ++ks)
#pragma unroll
        for (int j = 0; j < 4; ++j) { A[ks][j] = (short)f2bf(lo[ks][j]); A[ks][4 + j] = (short)f2bf(hi[ks][j]); }

    // ---- main loop ----
    while (true) {
        const bool have_next = (t + nw) < ntiles;
        // (1) issue F(t+nw): 12 independent 16 B loads (oldest in vmcnt queue)
        if (have_next) {
            const float* b0 = node + (size_t)siN * 64;
            const float* b1 = node + (size_t)tiN * 64;
            const float* b2 = edgef + (size_t)pN * 64;
#pragma unroll
            for (int ks = 0; ks < 6; ++ks) {
                const float* bb = (ks < 2) ? b0 : (ks < 4) ? b1 : b2;
                const float* pp = bb + (ks & 1) * 32 + g * 8;
                lo[ks] = *reinterpret_cast<const f32x4*>(pp);
                hi[ks] = *reinterpret_cast<const f32x4*>(pp + 4);
            }
        }
        // (2) issue idx(t+2nw)
        const int pN2 = posof(t + 2 * nw);
        const int siN2 = src[pN2], tiN2 = tgt[pN2];

        // (3) MFMA from registers (A) + LDS (B). lz launders the LDS base so
        // LICM can't hoist 24 loop-invariant b128 reads into 96 VGPRs.
        int lz;
        asm volatile("v_mov_b32 %0, 0" : "=v"(lz));
        const ushort* wbase = &WTs[0][0] + lz;
        f32x4 acc[4] = {{0.f,0.f,0.f,0.f},{0.f,0.f,0.f,0.f},{0.f,0.f,0.f,0.f},{0.f,0.f,0.f,0.f}};
#pragma unroll
        for (int ks = 0; ks < 6; ++ks)
#pragma unroll
            for (int nt = 0; nt < 4; ++nt) {
                const s16x8 bf = *reinterpret_cast<const s16x8*>(
                    wbase + (nt * 16 + r) * WT_LD + ks * 32 + g * 8);
                acc[nt] = __builtin_amdgcn_mfma_f32_16x16x32_bf16(A[ks], bf, acc[nt], 0, 0, 0);
            }

        // (4) wave-local epilogue: relu(acc+b) -> LDS transpose -> store at the
        // edge's SORTED position (rank). C/D layout: col = lane&15, row=(lane>>4)*4+j.
        const int tile0 = t * 16;
#pragma unroll
        for (int nt = 0; nt < 4; ++nt)
#pragma unroll
            for (int j = 0; j < 4; ++j)
                T[wave][g * 4 + j][nt * 16 + r] = f2bf(fmaxf(acc[nt][j] + bv[nt], 0.0f));
        asm volatile("s_waitcnt lgkmcnt(0)" ::: "memory");
        {
            const int row = lane >> 2, q = lane & 3;
            if (tile0 + row < n_edges) {
                const int rk = rank[tile0 + row];     // L2-resident (3.2 MB, just written)
                const s16x8 m0 = *reinterpret_cast<const s16x8*>(&T[wave][row][q * 16]);
                const s16x8 m1 = *reinterpret_cast<const s16x8*>(&T[wave][row][q * 16 + 8]);
                const size_t op = (size_t)rk * 64 + q * 16;
                *reinterpret_cast<s16x8*>(msg + op) = m0;
                *reinterpret_cast<s16x8*>(msg + op + 8) = m1;
            }
        }

        if (!have_next) break;
        t += nw;
        // (5) rotate: convert F(t) -> A (compiler waits vmcnt for F only; idx
        // loads are younger and stay outstanding).
#pragma unroll
        for (int ks = 0; ks < 6; ++ks)
#pragma unroll
            for (int j = 0; j < 4; ++j) { A[ks][j] = (short)f2bf(lo[ks][j]); A[ks][4 + j] = (short)f2bf(hi[ks][j]); }
        pN = pN2; siN = siN2; tiN = tiN2;
    }
}

// ---- Per-node pooling: CONTIGUOUS sorted runs, zero indirection ----
// (pool_gather minus the perm read; 16 B/lane, 8 rows in flight, shfl reduce)
__global__ __launch_bounds__(256) void pool_seq(
    const ushort* __restrict__ msg, const int* __restrict__ offsets,
    float* __restrict__ out, int n_nodes)
{
    const int wave = threadIdx.x >> 6, lane = threadIdx.x & 63;
    const int n = blockIdx.x * 4 + wave;
    if (n >= n_nodes) return;
    const int s = offsets[n], e = offsets[n + 1];
    const int c = lane & 7;    // feature chunk (8 features, 16 B)
    const int rg = lane >> 3;  // row group: 8 rows in flight
    float acc[8] = {0.f,0.f,0.f,0.f,0.f,0.f,0.f,0.f};
    for (int i = s + rg; i < e; i += 8) {
        const s16x8 v = *reinterpret_cast<const s16x8*>(msg + (size_t)i * 64 + c * 8);
#pragma unroll
        for (int j = 0; j < 8; ++j) acc[j] += bf2f((ushort)v[j]);
    }
#pragma unroll
    for (int j = 0; j < 8; ++j) {
        acc[j] += __shfl_xor(acc[j], 8, 64);
        acc[j] += __shfl_xor(acc[j], 16, 64);
        acc[j] += __shfl_xor(acc[j], 32, 64);
    }
    if (rg == 0) {
        const f32x4 o0 = {acc[0], acc[1], acc[2], acc[3]};
        const f32x4 o1 = {acc[4], acc[5], acc[6], acc[7]};
        *reinterpret_cast<f32x4*>(out + (size_t)n * 64 + c * 8) = o0;
        *reinterpret_cast<f32x4*>(out + (size_t)n * 64 + c * 8 + 4) = o1;
    }
}

// ---- Fallback: atomic scatter (only if ws too small) ----
__global__ __launch_bounds__(256) void edge_gemm_atomic(
    const float* __restrict__ node, const float* __restrict__ edgef,
    const int* __restrict__ src, const int* __restrict__ tgt,
    const ushort* __restrict__ WT, const float* __restrict__ bias,
    float* __restrict__ out, int n_edges)
{
    const int lane = threadIdx.x & 63;
    const int g = lane >> 4, r = lane & 15;
    const int tile0 = blockIdx.x * 64 + (threadIdx.x >> 6) * 16;
    int pos = tile0 + r; if (pos >= n_edges) pos = n_edges - 1;
    const int si = src[pos], ti = tgt[pos];
    const float* base0 = node + (size_t)si * 64;
    const float* base1 = node + (size_t)ti * 64;
    const float* base2 = edgef + (size_t)pos * 64;
    f32x4 acc[4] = {{0.f,0.f,0.f,0.f},{0.f,0.f,0.f,0.f},{0.f,0.f,0.f,0.f},{0.f,0.f,0.f,0.f}};
#pragma unroll
    for (int ks = 0; ks < 6; ++ks) {
        const float* b = (ks < 2) ? base0 : (ks < 4) ? base1 : base2;
        const float* p = b + (ks & 1) * 32 + g * 8;
        const f32x4 lo = *reinterpret_cast<const f32x4*>(p);
        const f32x4 hi = *reinterpret_cast<const f32x4*>(p + 4);
        s16x8 a;
#pragma unroll
        for (int j = 0; j < 4; ++j) { a[j] = (short)f2bf(lo[j]); a[4 + j] = (short)f2bf(hi[j]); }
#pragma unroll
        for (int nt = 0; nt < 4; ++nt) {
            const s16x8 bf = *reinterpret_cast<const s16x8*>(WT + (nt * 16 + r) * 192 + ks * 32 + g * 8);
            acc[nt] = __builtin_amdgcn_mfma_f32_16x16x32_bf16(a, bf, acc[nt], 0, 0, 0);
        }
    }
#pragma unroll
    for (int nt = 0; nt < 4; ++nt) {
        const float bv = bias[nt * 16 + r];
#pragma unroll
        for (int j = 0; j < 4; ++j) {
            const int e = tile0 + g * 4 + j;
            if (e < n_edges) {
                float v = fmaxf(acc[nt][j] + bv, 0.0f);
                unsafeAtomicAdd(out + (size_t)tgt[e] * 64 + nt * 16 + r, v);
            }
        }
    }
}

extern "C" void kernel_launch(void* const* d_in, const int* in_sizes, int n_in,
                              void* d_out, int out_size, void* d_ws, size_t ws_size,
                              hipStream_t stream) {
    const float* node  = (const float*)d_in[0];
    const float* edgef = (const float*)d_in[1];
    const int*   src   = (const int*)d_in[2];
    const int*   tgt   = (const int*)d_in[3];
    const float* W     = (const float*)d_in[4];
    const float* bias  = (const float*)d_in[5];
    float* out = (float*)d_out;
    const int n_edges = in_sizes[2];
    const int n_nodes = in_sizes[0] / 64;

    char* ws = (char*)d_ws;
    size_t cur = 0;
    auto take = [&](size_t b) { size_t s = cur; cur = (cur + b + 255) & ~(size_t)255; return s; };
    const size_t oWT   = take((size_t)64 * 192 * 2);
    const size_t oCnt  = take((size_t)n_nodes * 4);
    const size_t oOff  = take((size_t)(n_nodes + 1) * 4);
    const size_t oWoff = take((size_t)n_nodes * 4);
    const size_t oRank = take((size_t)n_edges * 4);
    const size_t oMsg  = take((size_t)n_edges * 64 * 2);
    const bool sorted_ok = (cur <= ws_size);

    ushort* WT = (ushort*)(ws + oWT);
    prep_wt<<<48, 256, 0, stream>>>(W, WT);

    if (sorted_ok) {
        int* counts  = (int*)(ws + oCnt);
        int* offsets = (int*)(ws + oOff);
        int* woff    = (int*)(ws + oWoff);
        int* rank    = (int*)(ws + oRank);
        ushort* msg  = (ushort*)(ws + oMsg);

        hipMemsetAsync(counts, 0, (size_t)n_nodes * 4, stream);
        hist_tgt<<<(n_edges + 255) / 256, 256, 0, stream>>>(tgt, counts, n_edges);
        scan_counts<<<1, 1024, 0, stream>>>(counts, offsets, woff, n_nodes, n_edges);
        build_rank<<<(n_edges + 255) / 256, 256, 0, stream>>>(tgt, woff, rank, n_edges);

        const int ntiles = (n_edges + 15) / 16;
        int blocks = 1024;
        if (blocks * 4 > ntiles) blocks = (ntiles + 3) / 4;
        edge_gemm_pipe<<<blocks, 256, 0, stream>>>(
            node, edgef, src, tgt, rank, WT, bias, msg, n_edges);
        pool_seq<<<(n_nodes + 3) / 4, 256, 0, stream>>>(msg, offsets, out, n_nodes);
    } else {
        hipMemsetAsync(d_out, 0, (size_t)out_size * sizeof(float), stream);
        edge_gemm_atomic<<<(n_edges + 63) / 64, 256, 0, stream>>>(
            node, edgef, src, tgt, WT, bias, out, n_edges);
    }
}